// Round 1
// baseline (718.527 us; speedup 1.0000x reference)
//
#include <hip/hip_runtime.h>
#include <hip/hip_bf16.h>

// GraphSAGE forward: N=50000 nodes, E=600000 edges, D=H=128, G=128 graphs.
// Pipeline:
//   x_pre = rownorm(x)
//   h   = leaky(l2norm(mean_agg(x_pre) @ W1l.T + x_pre @ W1r.T))
//   h1  = leaky([h | x_pre] @ fc1_W.T + fc1_b)
//   h2  = leaky(l2norm(mean_agg(h1) @ W2l.T + h1 @ W2r.T))
//   h3  = leaky([h2 | h1] @ fc2_W.T + fc2_b)
//   out = l2norm(leaky(segpool(h3) @ fc3_W.T + fc3_b))

#define NEG_SLOPE 0.01f
#define L2EPS 1e-12f

// ---------------- preprocess: row-normalize x ----------------
__global__ void k_preprocess(const float* __restrict__ x, float* __restrict__ xp, int N) {
    int node = blockIdx.x * 4 + (threadIdx.x >> 6);
    int lane = threadIdx.x & 63;
    if (node >= N) return;
    float2 v = ((const float2*)x)[(size_t)node * 64 + lane];
    float s = v.x + v.y;
    #pragma unroll
    for (int off = 32; off > 0; off >>= 1) s += __shfl_xor(s, off);
    float rinv = (s == 0.0f) ? 0.0f : 1.0f / s;
    float2 o; o.x = v.x * rinv; o.y = v.y * rinv;
    ((float2*)xp)[(size_t)node * 64 + lane] = o;
}

// ---------------- CSR build ----------------
__global__ void k_deg(const int* __restrict__ ei, int* __restrict__ deg, int E) {
    int e = blockIdx.x * blockDim.x + threadIdx.x;
    if (e >= E) return;
    atomicAdd(&deg[ei[E + e]], 1);
}

__global__ void k_scan(const int* __restrict__ deg, int* __restrict__ rs,
                       int* __restrict__ cursor, int N) {
    __shared__ int s[1024];
    __shared__ int carry_s;
    int t = threadIdx.x;
    if (t == 0) carry_s = 0;
    __syncthreads();
    for (int base = 0; base < N; base += 1024) {
        int i = base + t;
        int v = (i < N) ? deg[i] : 0;
        s[t] = v;
        __syncthreads();
        for (int off = 1; off < 1024; off <<= 1) {
            int add = (t >= off) ? s[t - off] : 0;
            __syncthreads();
            s[t] += add;
            __syncthreads();
        }
        int excl = carry_s + s[t] - v;
        if (i < N) { rs[i] = excl; cursor[i] = excl; }
        __syncthreads();
        if (t == 0) carry_s += s[1023];
        __syncthreads();
    }
    if (t == 0) rs[N] = carry_s;
}

__global__ void k_fill(const int* __restrict__ ei, int* __restrict__ cursor,
                       int* __restrict__ csr, int E) {
    int e = blockIdx.x * blockDim.x + threadIdx.x;
    if (e >= E) return;
    int src = ei[e];
    int dst = ei[E + e];
    int pos = atomicAdd(&cursor[dst], 1);
    csr[pos] = src;
}

// ---------------- mean aggregation (gather over CSR) ----------------
__global__ void k_agg(const float* __restrict__ feat, const int* __restrict__ csr,
                      const int* __restrict__ rs, float* __restrict__ mean, int N) {
    int node = blockIdx.x * 4 + (threadIdx.x >> 6);
    int lane = threadIdx.x & 63;
    if (node >= N) return;
    int beg = rs[node], end = rs[node + 1];
    float2 acc; acc.x = 0.f; acc.y = 0.f;
    const float2* f2 = (const float2*)feat;
    for (int p = beg; p < end; ++p) {
        int s = csr[p];
        float2 v = f2[(size_t)s * 64 + lane];
        acc.x += v.x; acc.y += v.y;
    }
    int d = end - beg;
    float inv = (d > 0) ? (1.0f / (float)d) : 0.0f;
    float2 o; o.x = acc.x * inv; o.y = acc.y * inv;
    ((float2*)mean)[(size_t)node * 64 + lane] = o;
}

// ---------------- fused dual-input GEMM: out = act([A1|A2] @ [Wa|Wb].T) ----------------
// BM=64 rows, BN=128 cols (full output width), K=256 (two halves of 128), BK=32.
// 256 threads: tx=t&31 -> 4 cols (tx*4), ty=t>>5 -> 8 rows (ty*8).
#define PADA 68   // 68*4 = 272 B, multiple of 16 -> aligned float4 LDS reads
#define PADW 132  // 132*4 = 528 B, multiple of 16

template <bool L2N, bool BIAS>
__global__ __launch_bounds__(256) void k_gemm2(
    const float* __restrict__ A1, const float* __restrict__ A2,
    const float* __restrict__ Wa, int ldwa,
    const float* __restrict__ Wb, int ldwb,
    const float* __restrict__ bias,
    float* __restrict__ out, int N)
{
    __shared__ float As[32][PADA];
    __shared__ float Ws[32][PADW];
    int t = threadIdx.x;
    int tx = t & 31, ty = t >> 5;
    int i0 = blockIdx.x * 64;

    float acc[8][4];
    #pragma unroll
    for (int j = 0; j < 8; ++j)
        #pragma unroll
        for (int i = 0; i < 4; ++i) acc[j][i] = 0.f;

    int a_r  = t >> 2;        // 0..63
    int a_kc = (t & 3) * 4;   // 0,4,8,12 (second chunk +16)
    int w_f0 = t >> 3;        // 0..31  (+32*it)
    int w_kc = (t & 7) * 4;   // 0..28

    for (int kb = 0; kb < 8; ++kb) {
        const float* Asrc; const float* Wsrc; int ldw;
        int kloc = (kb & 3) * 32;
        if (kb < 4) { Asrc = A1; Wsrc = Wa; ldw = ldwa; }
        else        { Asrc = A2; Wsrc = Wb; ldw = ldwb; }

        int grow = i0 + a_r;
        float4 av0, av1;
        if (grow < N) {
            const float* ap = Asrc + (size_t)grow * 128 + kloc;
            av0 = *(const float4*)(ap + a_kc);
            av1 = *(const float4*)(ap + a_kc + 16);
        } else {
            av0 = make_float4(0.f, 0.f, 0.f, 0.f);
            av1 = make_float4(0.f, 0.f, 0.f, 0.f);
        }
        float4 wv[4];
        #pragma unroll
        for (int it = 0; it < 4; ++it) {
            int f = w_f0 + 32 * it;
            wv[it] = *(const float4*)(Wsrc + (size_t)f * ldw + kloc + w_kc);
        }

        __syncthreads();  // previous tile fully consumed
        #pragma unroll
        for (int jj = 0; jj < 4; ++jj) As[a_kc + jj][a_r]      = ((const float*)&av0)[jj];
        #pragma unroll
        for (int jj = 0; jj < 4; ++jj) As[a_kc + 16 + jj][a_r] = ((const float*)&av1)[jj];
        #pragma unroll
        for (int it = 0; it < 4; ++it) {
            int f = w_f0 + 32 * it;
            #pragma unroll
            for (int jj = 0; jj < 4; ++jj) Ws[w_kc + jj][f] = ((const float*)&wv[it])[jj];
        }
        __syncthreads();

        #pragma unroll
        for (int k = 0; k < 32; ++k) {
            float4 a0 = *(const float4*)&As[k][ty * 8];
            float4 a1 = *(const float4*)&As[k][ty * 8 + 4];
            float4 w  = *(const float4*)&Ws[k][tx * 4];
            float ar[8] = {a0.x, a0.y, a0.z, a0.w, a1.x, a1.y, a1.z, a1.w};
            float wr[4] = {w.x, w.y, w.z, w.w};
            #pragma unroll
            for (int j = 0; j < 8; ++j)
                #pragma unroll
                for (int i = 0; i < 4; ++i) acc[j][i] += ar[j] * wr[i];
        }
    }

    // epilogue
    float scale[8];
    if (L2N) {
        #pragma unroll
        for (int j = 0; j < 8; ++j) {
            float s = acc[j][0]*acc[j][0] + acc[j][1]*acc[j][1]
                    + acc[j][2]*acc[j][2] + acc[j][3]*acc[j][3];
            #pragma unroll
            for (int off = 1; off < 32; off <<= 1) s += __shfl_xor(s, off);
            scale[j] = 1.0f / fmaxf(sqrtf(s), L2EPS);
        }
    }
    float b[4];
    if (BIAS) {
        #pragma unroll
        for (int i = 0; i < 4; ++i) b[i] = bias[tx * 4 + i];
    }
    #pragma unroll
    for (int j = 0; j < 8; ++j) {
        int row = i0 + ty * 8 + j;
        if (row >= N) continue;
        float4 v; float* vp = (float*)&v;
        #pragma unroll
        for (int i = 0; i < 4; ++i) {
            float xv = acc[j][i];
            if (L2N) xv *= scale[j];
            if (BIAS) xv += b[i];
            vp[i] = (xv >= 0.f) ? xv : NEG_SLOPE * xv;
        }
        *(float4*)(out + (size_t)row * 128 + tx * 4) = v;
    }
}

// ---------------- graph boundaries (batch is sorted) ----------------
__global__ void k_bounds(const int* __restrict__ batch, int* __restrict__ gs, int N, int G) {
    int g = threadIdx.x;
    if (g > G) return;
    int lo = 0, hi = N;
    while (lo < hi) {
        int m = (lo + hi) >> 1;
        if (batch[m] < g) lo = m + 1; else hi = m;
    }
    gs[g] = lo;
}

__global__ void k_pool(const float* __restrict__ h3, const int* __restrict__ gs,
                       float* __restrict__ pooled) {
    int g = blockIdx.x, f = threadIdx.x;
    int beg = gs[g], end = gs[g + 1];
    float acc = 0.f;
    for (int i = beg; i < end; ++i) acc += h3[(size_t)i * 128 + f];
    pooled[g * 128 + f] = acc;
}

__global__ void k_fc3(const float* __restrict__ pooled, const float* __restrict__ W,
                      const float* __restrict__ b, float* __restrict__ out) {
    int g = blockIdx.x, f = threadIdx.x;
    __shared__ float prow[128];
    __shared__ float red[128];
    prow[f] = pooled[g * 128 + f];
    __syncthreads();
    float acc = b[f];
    #pragma unroll 8
    for (int k = 0; k < 128; ++k) acc += prow[k] * W[f * 128 + k];
    float v = (acc >= 0.f) ? acc : NEG_SLOPE * acc;
    red[f] = v * v;
    __syncthreads();
    for (int o = 64; o > 0; o >>= 1) {
        if (f < o) red[f] += red[f + o];
        __syncthreads();
    }
    float sc = 1.0f / fmaxf(sqrtf(red[0]), L2EPS);
    out[g * 128 + f] = v * sc;
}

// ---------------- launch ----------------
extern "C" void kernel_launch(void* const* d_in, const int* in_sizes, int n_in,
                              void* d_out, int out_size, void* d_ws, size_t ws_size,
                              hipStream_t stream) {
    const float* x    = (const float*)d_in[0];
    const int*   ei   = (const int*)d_in[1];
    const int*   batch= (const int*)d_in[2];
    const float* W1l  = (const float*)d_in[3];
    const float* W1r  = (const float*)d_in[4];
    const float* W2l  = (const float*)d_in[5];
    const float* W2r  = (const float*)d_in[6];
    const float* fc1W = (const float*)d_in[7];
    const float* fc1b = (const float*)d_in[8];
    const float* fc2W = (const float*)d_in[9];
    const float* fc2b = (const float*)d_in[10];
    const float* fc3W = (const float*)d_in[11];
    const float* fc3b = (const float*)d_in[12];

    int N = in_sizes[0] / 128;
    int E = in_sizes[1] / 2;
    int G = out_size / 128;
    float* out = (float*)d_out;

    char* ws = (char*)d_ws;
    size_t off = 0;
    auto alloc = [&](size_t bytes) -> void* {
        void* p = ws + off;
        off = (off + bytes + 255) & ~(size_t)255;
        return p;
    };
    float* xp     = (float*)alloc((size_t)N * 128 * 4);  // x_pre, later reused as h3
    float* mean   = (float*)alloc((size_t)N * 128 * 4);
    float* h      = (float*)alloc((size_t)N * 128 * 4);  // h, later h2
    float* h1     = (float*)alloc((size_t)N * 128 * 4);
    float* pooled = (float*)alloc((size_t)G * 128 * 4);
    int* deg      = (int*)alloc((size_t)N * 4);
    int* rs       = (int*)alloc((size_t)(N + 1) * 4);
    int* cursor   = (int*)alloc((size_t)N * 4);
    int* csr      = (int*)alloc((size_t)E * 4);
    int* gs       = (int*)alloc((size_t)(G + 1) * 4);
    (void)ws_size; (void)n_in;

    hipMemsetAsync(deg, 0, (size_t)N * 4, stream);

    k_preprocess<<<(N + 3) / 4, 256, 0, stream>>>(x, xp, N);
    k_deg<<<(E + 255) / 256, 256, 0, stream>>>(ei, deg, E);
    k_scan<<<1, 1024, 0, stream>>>(deg, rs, cursor, N);
    k_fill<<<(E + 255) / 256, 256, 0, stream>>>(ei, cursor, csr, E);

    // conv1 + fc1
    k_agg<<<(N + 3) / 4, 256, 0, stream>>>(xp, csr, rs, mean, N);
    k_gemm2<true, false><<<(N + 63) / 64, 256, 0, stream>>>(
        mean, xp, W1l, 128, W1r, 128, nullptr, h, N);
    k_gemm2<false, true><<<(N + 63) / 64, 256, 0, stream>>>(
        h, xp, fc1W, 256, fc1W + 128, 256, fc1b, h1, N);

    // conv2 + fc2 (h2 -> h buffer, h3 -> xp buffer)
    k_agg<<<(N + 3) / 4, 256, 0, stream>>>(h1, csr, rs, mean, N);
    k_gemm2<true, false><<<(N + 63) / 64, 256, 0, stream>>>(
        mean, h1, W2l, 128, W2r, 128, nullptr, h, N);
    k_gemm2<false, true><<<(N + 63) / 64, 256, 0, stream>>>(
        h, h1, fc2W, 256, fc2W + 128, 256, fc2b, xp, N);

    // pool + head
    k_bounds<<<1, 256, 0, stream>>>(batch, gs, N, G);
    k_pool<<<G, 128, 0, stream>>>(xp, gs, pooled);
    k_fc3<<<G, 128, 0, stream>>>(pooled, fc3W, fc3b, out);
}

// Round 2
// 595.127 us; speedup vs baseline: 1.2074x; 1.2074x over previous
//
#include <hip/hip_runtime.h>
#include <hip/hip_bf16.h>

// GraphSAGE forward: N=50000 nodes, E=600000 edges, D=H=128, G=128 graphs.
//   x_pre = rownorm(x)
//   h   = leaky(l2norm(mean_agg(x_pre) @ W1l.T + x_pre @ W1r.T))
//   h1  = leaky([h | x_pre] @ fc1_W.T + fc1_b)
//   h2  = leaky(l2norm(mean_agg(h1) @ W2l.T + h1 @ W2r.T))
//   h3  = leaky([h2 | h1] @ fc2_W.T + fc2_b)
//   out = l2norm(leaky(segpool(h3) @ fc3_W.T + fc3_b))

#define NEG_SLOPE 0.01f
#define L2EPS 1e-12f

// ---------------- preprocess: row-normalize x ----------------
__global__ void k_preprocess(const float* __restrict__ x, float* __restrict__ xp, int N) {
    int node = blockIdx.x * 4 + (threadIdx.x >> 6);
    int lane = threadIdx.x & 63;
    if (node >= N) return;
    float2 v = ((const float2*)x)[(size_t)node * 64 + lane];
    float s = v.x + v.y;
    #pragma unroll
    for (int off = 32; off > 0; off >>= 1) s += __shfl_xor(s, off);
    float rinv = (s == 0.0f) ? 0.0f : 1.0f / s;
    float2 o; o.x = v.x * rinv; o.y = v.y * rinv;
    ((float2*)xp)[(size_t)node * 64 + lane] = o;
}

// ---------------- CSR build ----------------
__global__ void k_deg(const int* __restrict__ ei, int* __restrict__ deg, int E) {
    int e = blockIdx.x * blockDim.x + threadIdx.x;
    if (e >= E) return;
    atomicAdd(&deg[ei[E + e]], 1);
}

// single-block scan, wave-shuffle based: 3 barriers per 1024-chunk
__global__ void k_scan(const int* __restrict__ deg, int* __restrict__ rs,
                       int* __restrict__ cursor, int N) {
    __shared__ int wsum[16];
    __shared__ int carry_s;
    int t = threadIdx.x;
    int lane = t & 63, w = t >> 6;
    if (t == 0) carry_s = 0;
    __syncthreads();
    for (int base = 0; base < N; base += 1024) {
        int i = base + t;
        int v = (i < N) ? deg[i] : 0;
        // inclusive wave scan
        int s = v;
        #pragma unroll
        for (int off = 1; off < 64; off <<= 1) {
            int u = __shfl_up(s, off);
            if (lane >= off) s += u;
        }
        if (lane == 63) wsum[w] = s;
        __syncthreads();
        if (w == 0) {
            int x = (lane < 16) ? wsum[lane] : 0;
            #pragma unroll
            for (int off = 1; off < 16; off <<= 1) {
                int u = __shfl_up(x, off);
                if (lane >= off) x += u;
            }
            if (lane < 16) wsum[lane] = x;  // inclusive wave-sum scan
        }
        __syncthreads();
        int wexcl = (w == 0) ? 0 : wsum[w - 1];
        int excl = carry_s + wexcl + (s - v);
        if (i < N) { rs[i] = excl; cursor[i] = excl; }
        __syncthreads();  // all reads of carry_s/wsum done
        if (t == 0) carry_s += wsum[15];
        __syncthreads();
    }
    if (t == 0) rs[N] = carry_s;
}

__global__ void k_fill(const int* __restrict__ ei, int* __restrict__ cursor,
                       int* __restrict__ csr, int E) {
    int e = blockIdx.x * blockDim.x + threadIdx.x;
    if (e >= E) return;
    int src = ei[e];
    int dst = ei[E + e];
    int pos = atomicAdd(&cursor[dst], 1);
    csr[pos] = src;
}

// ---------------- mean aggregation (gather over CSR) ----------------
__global__ void k_agg(const float* __restrict__ feat, const int* __restrict__ csr,
                      const int* __restrict__ rs, float* __restrict__ mean, int N) {
    int node = blockIdx.x * 4 + (threadIdx.x >> 6);
    int lane = threadIdx.x & 63;
    if (node >= N) return;
    int beg = rs[node], end = rs[node + 1];
    float2 acc; acc.x = 0.f; acc.y = 0.f;
    const float2* f2 = (const float2*)feat;
    for (int p = beg; p < end; ++p) {
        int s = csr[p];
        float2 v = f2[(size_t)s * 64 + lane];
        acc.x += v.x; acc.y += v.y;
    }
    int d = end - beg;
    float inv = (d > 0) ? (1.0f / (float)d) : 0.0f;
    float2 o; o.x = acc.x * inv; o.y = acc.y * inv;
    ((float2*)mean)[(size_t)node * 64 + lane] = o;
}

// ---------------- fused dual-input GEMM: out = act([A1|A2] @ [Wa|Wb].T) ----------------
// BM=128 rows, BN=128 cols, K=256 (two halves of 128), BK=32.
// 256 threads: tx=t&15 -> 8 cols (tx*8), ty=t>>4 -> 8 rows (ty*8). 8x8 per thread.
#define LDT 132  // 132*4 = 528 B row stride, multiple of 16

// XOR swizzle on W columns: breaks the 4-way conflict of the stride-8 col read.
__device__ __forceinline__ int wswz(int c) { return c ^ (((c >> 5) & 3) << 2); }

template <bool L2N, bool BIAS>
__global__ __launch_bounds__(256) void k_gemm2(
    const float* __restrict__ A1, const float* __restrict__ A2,
    const float* __restrict__ Wa, int ldwa,
    const float* __restrict__ Wb, int ldwb,
    const float* __restrict__ bias,
    float* __restrict__ out, int N)
{
    __shared__ float As[32][LDT];
    __shared__ float Ws[32][LDT];
    int t = threadIdx.x;
    int tx = t & 15, ty = t >> 4;
    int i0 = blockIdx.x * 128;

    float acc[8][8];
    #pragma unroll
    for (int j = 0; j < 8; ++j)
        #pragma unroll
        for (int i = 0; i < 8; ++i) acc[j][i] = 0.f;

    int a_r  = t >> 1;        // 0..127 (row of A / feature row of W)
    int a_kc = (t & 1) * 16;  // 0 or 16 (16 consecutive k per thread)

    for (int kb = 0; kb < 8; ++kb) {
        const float* Asrc; const float* Wsrc; int ldw;
        int kloc = (kb & 3) * 32;
        if (kb < 4) { Asrc = A1; Wsrc = Wa; ldw = ldwa; }
        else        { Asrc = A2; Wsrc = Wb; ldw = ldwb; }

        int grow = i0 + a_r;
        float4 av[4];
        if (grow < N) {
            const float* ap = Asrc + (size_t)grow * 128 + kloc + a_kc;
            #pragma unroll
            for (int q = 0; q < 4; ++q) av[q] = *(const float4*)(ap + q * 4);
        } else {
            #pragma unroll
            for (int q = 0; q < 4; ++q) av[q] = make_float4(0.f, 0.f, 0.f, 0.f);
        }
        float4 wv[4];
        {
            const float* wp = Wsrc + (size_t)a_r * ldw + kloc + a_kc;
            #pragma unroll
            for (int q = 0; q < 4; ++q) wv[q] = *(const float4*)(wp + q * 4);
        }

        __syncthreads();  // previous tile fully consumed
        int fsw = wswz(a_r);
        #pragma unroll
        for (int q = 0; q < 4; ++q) {
            #pragma unroll
            for (int jj = 0; jj < 4; ++jj) {
                As[a_kc + q * 4 + jj][a_r] = ((const float*)&av[q])[jj];
                Ws[a_kc + q * 4 + jj][fsw] = ((const float*)&wv[q])[jj];
            }
        }
        __syncthreads();

        int wc0 = wswz(tx * 8), wc1 = wswz(tx * 8 + 4);
        #pragma unroll
        for (int k = 0; k < 32; ++k) {
            float4 a0 = *(const float4*)&As[k][ty * 8];
            float4 a1 = *(const float4*)&As[k][ty * 8 + 4];
            float4 w0 = *(const float4*)&Ws[k][wc0];
            float4 w1 = *(const float4*)&Ws[k][wc1];
            float ar[8] = {a0.x, a0.y, a0.z, a0.w, a1.x, a1.y, a1.z, a1.w};
            float wr[8] = {w0.x, w0.y, w0.z, w0.w, w1.x, w1.y, w1.z, w1.w};
            #pragma unroll
            for (int j = 0; j < 8; ++j)
                #pragma unroll
                for (int i = 0; i < 8; ++i) acc[j][i] += ar[j] * wr[i];
        }
    }

    // epilogue
    float scale[8];
    if (L2N) {
        #pragma unroll
        for (int j = 0; j < 8; ++j) {
            float s = 0.f;
            #pragma unroll
            for (int i = 0; i < 8; ++i) s += acc[j][i] * acc[j][i];
            #pragma unroll
            for (int off = 1; off < 16; off <<= 1) s += __shfl_xor(s, off);
            scale[j] = 1.0f / fmaxf(sqrtf(s), L2EPS);
        }
    }
    float b[8];
    if (BIAS) {
        #pragma unroll
        for (int i = 0; i < 8; ++i) b[i] = bias[tx * 8 + i];
    }
    #pragma unroll
    for (int j = 0; j < 8; ++j) {
        int row = i0 + ty * 8 + j;
        if (row >= N) continue;
        float4 v0, v1; float* vp0 = (float*)&v0; float* vp1 = (float*)&v1;
        #pragma unroll
        for (int i = 0; i < 8; ++i) {
            float xv = acc[j][i];
            if (L2N) xv *= scale[j];
            if (BIAS) xv += b[i];
            float r = (xv >= 0.f) ? xv : NEG_SLOPE * xv;
            if (i < 4) vp0[i] = r; else vp1[i - 4] = r;
        }
        float* op = out + (size_t)row * 128 + tx * 8;
        *(float4*)op = v0;
        *(float4*)(op + 4) = v1;
    }
}

// ---------------- pool: chunked partial sums over sorted batch ----------------
#define POOL_ROWS 128
__global__ void k_pool(const float* __restrict__ h3, const int* __restrict__ batch,
                       float* __restrict__ pooled, int N) {
    int f = threadIdx.x;  // 0..127
    int base = blockIdx.x * POOL_ROWS;
    if (base >= N) return;
    int end = min(base + POOL_ROWS, N);
    float acc = 0.f;
    int cur = batch[base];
    for (int i = base; i < end; ++i) {
        int g = batch[i];
        if (g != cur) {
            atomicAdd(&pooled[cur * 128 + f], acc);
            acc = 0.f; cur = g;
        }
        acc += h3[(size_t)i * 128 + f];
    }
    atomicAdd(&pooled[cur * 128 + f], acc);
}

__global__ void k_fc3(const float* __restrict__ pooled, const float* __restrict__ W,
                      const float* __restrict__ b, float* __restrict__ out) {
    int g = blockIdx.x, f = threadIdx.x;
    __shared__ float prow[128];
    __shared__ float red[128];
    prow[f] = pooled[g * 128 + f];
    __syncthreads();
    float acc = b[f];
    #pragma unroll 8
    for (int k = 0; k < 128; ++k) acc += prow[k] * W[f * 128 + k];
    float v = (acc >= 0.f) ? acc : NEG_SLOPE * acc;
    red[f] = v * v;
    __syncthreads();
    for (int o = 64; o > 0; o >>= 1) {
        if (f < o) red[f] += red[f + o];
        __syncthreads();
    }
    float sc = 1.0f / fmaxf(sqrtf(red[0]), L2EPS);
    out[g * 128 + f] = v * sc;
}

// ---------------- launch ----------------
extern "C" void kernel_launch(void* const* d_in, const int* in_sizes, int n_in,
                              void* d_out, int out_size, void* d_ws, size_t ws_size,
                              hipStream_t stream) {
    const float* x    = (const float*)d_in[0];
    const int*   ei   = (const int*)d_in[1];
    const int*   batch= (const int*)d_in[2];
    const float* W1l  = (const float*)d_in[3];
    const float* W1r  = (const float*)d_in[4];
    const float* W2l  = (const float*)d_in[5];
    const float* W2r  = (const float*)d_in[6];
    const float* fc1W = (const float*)d_in[7];
    const float* fc1b = (const float*)d_in[8];
    const float* fc2W = (const float*)d_in[9];
    const float* fc2b = (const float*)d_in[10];
    const float* fc3W = (const float*)d_in[11];
    const float* fc3b = (const float*)d_in[12];

    int N = in_sizes[0] / 128;
    int E = in_sizes[1] / 2;
    int G = out_size / 128;
    float* out = (float*)d_out;

    char* ws = (char*)d_ws;
    size_t off = 0;
    auto alloc = [&](size_t bytes) -> void* {
        void* p = ws + off;
        off = (off + bytes + 255) & ~(size_t)255;
        return p;
    };
    float* xp     = (float*)alloc((size_t)N * 128 * 4);  // x_pre, later reused as h3
    float* mean   = (float*)alloc((size_t)N * 128 * 4);
    float* h      = (float*)alloc((size_t)N * 128 * 4);  // h, later h2
    float* h1     = (float*)alloc((size_t)N * 128 * 4);
    float* pooled = (float*)alloc((size_t)G * 128 * 4);
    int* deg      = (int*)alloc((size_t)N * 4);
    int* rs       = (int*)alloc((size_t)(N + 1) * 4);
    int* cursor   = (int*)alloc((size_t)N * 4);
    int* csr      = (int*)alloc((size_t)E * 4);
    (void)ws_size; (void)n_in;

    hipMemsetAsync(deg, 0, (size_t)N * 4, stream);
    hipMemsetAsync(pooled, 0, (size_t)G * 128 * 4, stream);

    k_preprocess<<<(N + 3) / 4, 256, 0, stream>>>(x, xp, N);
    k_deg<<<(E + 255) / 256, 256, 0, stream>>>(ei, deg, E);
    k_scan<<<1, 1024, 0, stream>>>(deg, rs, cursor, N);
    k_fill<<<(E + 255) / 256, 256, 0, stream>>>(ei, cursor, csr, E);

    // conv1 + fc1
    k_agg<<<(N + 3) / 4, 256, 0, stream>>>(xp, csr, rs, mean, N);
    k_gemm2<true, false><<<(N + 127) / 128, 256, 0, stream>>>(
        mean, xp, W1l, 128, W1r, 128, nullptr, h, N);
    k_gemm2<false, true><<<(N + 127) / 128, 256, 0, stream>>>(
        h, xp, fc1W, 256, fc1W + 128, 256, fc1b, h1, N);

    // conv2 + fc2 (h2 -> h buffer, h3 -> xp buffer)
    k_agg<<<(N + 3) / 4, 256, 0, stream>>>(h1, csr, rs, mean, N);
    k_gemm2<true, false><<<(N + 127) / 128, 256, 0, stream>>>(
        mean, h1, W2l, 128, W2r, 128, nullptr, h, N);
    k_gemm2<false, true><<<(N + 127) / 128, 256, 0, stream>>>(
        h, h1, fc2W, 256, fc2W + 128, 256, fc2b, xp, N);

    // pool + head
    k_pool<<<(N + POOL_ROWS - 1) / POOL_ROWS, 128, 0, stream>>>(xp, batch, pooled, N);
    k_fc3<<<G, 128, 0, stream>>>(pooled, fc3W, fc3b, out);
}